// Round 1
// baseline (449.538 us; speedup 1.0000x reference)
//
#include <hip/hip_runtime.h>

#define NN 50000
#define NE 600000

// ---------------- graph build ----------------

__global__ void k_zero(int* cnt, int* fill) {
    int i = blockIdx.x * 256 + threadIdx.x;
    if (i < NN) { cnt[i] = 0; fill[i] = 0; }
}

__global__ void k_count(const int* __restrict__ ei, int* __restrict__ cnt) {
    int e = blockIdx.x * 256 + threadIdx.x;
    if (e < NE) atomicAdd(&cnt[ei[NE + e]], 1);
}

__global__ void k_dinv(const int* __restrict__ cnt, float* __restrict__ dinv) {
    int i = blockIdx.x * 256 + threadIdx.x;
    if (i < NN) dinv[i] = rsqrtf(1.0f + (float)cnt[i]);
}

// hierarchical exclusive scan of cnt -> rowptr
__global__ void k_scan1(const int* __restrict__ cnt, int* __restrict__ rowptr,
                        int* __restrict__ bsum) {
    __shared__ int s[256];
    int t = threadIdx.x;
    int i = blockIdx.x * 256 + t;
    int v = (i < NN) ? cnt[i] : 0;
    s[t] = v;
    __syncthreads();
    for (int d = 1; d < 256; d <<= 1) {
        int tmp = (t >= d) ? s[t - d] : 0;
        __syncthreads();
        s[t] += tmp;
        __syncthreads();
    }
    if (i < NN) rowptr[i] = s[t] - v;   // exclusive
    if (t == 255) bsum[blockIdx.x] = s[255];
}

__global__ void k_scan2(int* __restrict__ bsum, int* __restrict__ boff, int nb) {
    __shared__ int s[256];
    int t = threadIdx.x;
    int v = (t < nb) ? bsum[t] : 0;
    s[t] = v;
    __syncthreads();
    for (int d = 1; d < 256; d <<= 1) {
        int tmp = (t >= d) ? s[t - d] : 0;
        __syncthreads();
        s[t] += tmp;
        __syncthreads();
    }
    boff[t] = s[t] - v;   // exclusive
}

__global__ void k_scan3(int* __restrict__ rowptr, const int* __restrict__ boff) {
    int i = blockIdx.x * 256 + threadIdx.x;
    if (i < NN) rowptr[i] += boff[blockIdx.x];
}

__global__ void k_fill(const int* __restrict__ ei, const int* __restrict__ rowptr,
                       int* __restrict__ fill, const float* __restrict__ dinv,
                       int* __restrict__ col, float* __restrict__ val) {
    int e = blockIdx.x * 256 + threadIdx.x;
    if (e < NE) {
        int s = ei[e];
        int d = ei[NE + e];
        int pos = rowptr[d] + atomicAdd(&fill[d], 1);
        col[pos] = s;
        val[pos] = dinv[s] * dinv[d];
    }
}

// ---------------- GEMM [N,128] @ [128,128] fp32 ----------------
// block: 256 threads, tile 128 rows x 128 cols, thread 8x8 register tile.
// W fully in LDS (64KB); x k-panel (16) staged transposed, padded to 132.
__global__ __launch_bounds__(256, 2) void k_gemm128(const float* __restrict__ X,
                                                    const float* __restrict__ W,
                                                    float* __restrict__ C, int nrows) {
    __shared__ float Wl[128 * 128];
    __shared__ float xT[16 * 132];
    int t = threadIdx.x;

    // load W straight (row-major) -- coalesced, conflict-free b128 writes
    const float4* W4 = (const float4*)W;
    float4* Wl4 = (float4*)Wl;
#pragma unroll
    for (int j = 0; j < 16; ++j) Wl4[t + j * 256] = W4[t + j * 256];

    int rowBase = blockIdx.x * 128;
    int rg = t >> 4, cg = t & 15;
    int r0 = rg * 8;
    int ca = cg * 4;          // cols [4cg..4cg+3]
    int cb = 64 + cg * 4;     // cols [64+4cg..] -> spreads banks across 16 lanes
    int chunk = t & 3, rr = t >> 2;

    float acc[8][8] = {};

    for (int p = 0; p < 8; ++p) {
        int k0 = p * 16;
        // stage x panel transposed: xT[kk][row], pad 132 (2-way bank alias = free)
#pragma unroll
        for (int ps = 0; ps < 2; ++ps) {
            int r = rr + ps * 64;
            int gr = rowBase + r;
            float4 g = {0.f, 0.f, 0.f, 0.f};
            if (gr < nrows) g = ((const float4*)X)[gr * 32 + (k0 >> 2) + chunk];
            xT[(chunk * 4 + 0) * 132 + r] = g.x;
            xT[(chunk * 4 + 1) * 132 + r] = g.y;
            xT[(chunk * 4 + 2) * 132 + r] = g.z;
            xT[(chunk * 4 + 3) * 132 + r] = g.w;
        }
        __syncthreads();
#pragma unroll
        for (int kk = 0; kk < 16; ++kk) {
            int krow = k0 + kk;
            float4 xa = *(const float4*)&xT[kk * 132 + r0];
            float4 xb = *(const float4*)&xT[kk * 132 + r0 + 4];
            float4 wa = *(const float4*)&Wl[krow * 128 + ca];
            float4 wb = *(const float4*)&Wl[krow * 128 + cb];
            float xs[8] = {xa.x, xa.y, xa.z, xa.w, xb.x, xb.y, xb.z, xb.w};
            float ws[8] = {wa.x, wa.y, wa.z, wa.w, wb.x, wb.y, wb.z, wb.w};
#pragma unroll
            for (int i = 0; i < 8; ++i)
#pragma unroll
                for (int j = 0; j < 8; ++j) acc[i][j] += xs[i] * ws[j];
        }
        __syncthreads();
    }

#pragma unroll
    for (int i = 0; i < 8; ++i) {
        int gr = rowBase + r0 + i;
        if (gr < nrows) {
            float4 va = {acc[i][0], acc[i][1], acc[i][2], acc[i][3]};
            float4 vb = {acc[i][4], acc[i][5], acc[i][6], acc[i][7]};
            ((float4*)C)[gr * 32 + cg] = va;
            ((float4*)C)[gr * 32 + 16 + cg] = vb;
        }
    }
}

// ---------------- small GEMM [N,128] @ [128,CO] ----------------
template <int CO>
__global__ void k_gemm_small(const float* __restrict__ X, const float* __restrict__ W,
                             float* __restrict__ C) {
    __shared__ float Wt[CO * 128];   // transposed: Wt[c][k]
    int t = threadIdx.x;
    for (int j = t; j < 128 * CO; j += 256) {
        int k = j / CO, c = j % CO;
        Wt[c * 128 + k] = W[j];
    }
    __syncthreads();
    int row = blockIdx.x * 256 + t;
    if (row >= NN) return;
    const float4* X4 = (const float4*)X;
    float acc[CO] = {};
#pragma unroll 4
    for (int kc = 0; kc < 32; ++kc) {
        float4 xv = X4[row * 32 + kc];
#pragma unroll
        for (int c = 0; c < CO; ++c) {
            acc[c] += xv.x * Wt[c * 128 + kc * 4 + 0] + xv.y * Wt[c * 128 + kc * 4 + 1] +
                      xv.z * Wt[c * 128 + kc * 4 + 2] + xv.w * Wt[c * 128 + kc * 4 + 3];
        }
    }
#pragma unroll
    for (int c = 0; c < CO; ++c) C[row * CO + c] = acc[c];
}

// ---------------- aggregation, 128 features ----------------
// one wave per node; two edges in flight (half-wave x float4); shfl_xor combine.
__global__ __launch_bounds__(256) void k_agg128(const float* __restrict__ H,
                                                float* __restrict__ OUT,
                                                const float* __restrict__ bias,
                                                const float* __restrict__ dinv,
                                                const int* __restrict__ rowptr,
                                                const int* __restrict__ cnt,
                                                const int* __restrict__ col,
                                                const float* __restrict__ val, int relu) {
    int wv = threadIdx.x >> 6;
    int l = threadIdx.x & 63;
    int i = blockIdx.x * 4 + wv;
    if (i >= NN) return;
    int half = l >> 5, lf = l & 31;
    const float4* H4 = (const float4*)H;

    float4 acc = {0.f, 0.f, 0.f, 0.f};
    float di = dinv[i];
    if (half == 0) {   // self loop, weight dinv^2
        float4 h = H4[i * 32 + lf];
        float w = di * di;
        acc.x = w * h.x; acc.y = w * h.y; acc.z = w * h.z; acc.w = w * h.w;
    }
    int st = rowptr[i];
    int n = cnt[i];
    for (int j = half; j < n; j += 2) {
        int e = st + j;
        int s = col[e];
        float w = val[e];
        float4 h = H4[s * 32 + lf];
        acc.x += w * h.x; acc.y += w * h.y; acc.z += w * h.z; acc.w += w * h.w;
    }
    acc.x += __shfl_xor(acc.x, 32, 64);
    acc.y += __shfl_xor(acc.y, 32, 64);
    acc.z += __shfl_xor(acc.z, 32, 64);
    acc.w += __shfl_xor(acc.w, 32, 64);
    if (half == 0) {
        float4 b = ((const float4*)bias)[lf];
        float4 r;
        r.x = acc.x + b.x; r.y = acc.y + b.y; r.z = acc.z + b.z; r.w = acc.w + b.w;
        if (relu) {
            r.x = fmaxf(r.x, 0.f); r.y = fmaxf(r.y, 0.f);
            r.z = fmaxf(r.z, 0.f); r.w = fmaxf(r.w, 0.f);
        }
        ((float4*)OUT)[i * 32 + lf] = r;
    }
}

// ---------------- aggregation, CO features (8 or 1), no relu ----------------
template <int CO>
__global__ void k_agg_small(const float* __restrict__ H, float* __restrict__ OUT,
                            const float* __restrict__ bias, const float* __restrict__ dinv,
                            const int* __restrict__ rowptr, const int* __restrict__ cnt,
                            const int* __restrict__ col, const float* __restrict__ val) {
    int i = blockIdx.x * 256 + threadIdx.x;
    if (i >= NN) return;
    float di = dinv[i];
    float w0 = di * di;
    float acc[CO];
#pragma unroll
    for (int c = 0; c < CO; ++c) acc[c] = w0 * H[i * CO + c];
    int st = rowptr[i];
    int n = cnt[i];
    for (int j = 0; j < n; ++j) {
        int e = st + j;
        int s = col[e];
        float w = val[e];
#pragma unroll
        for (int c = 0; c < CO; ++c) acc[c] += w * H[s * CO + c];
    }
#pragma unroll
    for (int c = 0; c < CO; ++c) OUT[i * CO + c] = acc[c] + bias[c];
}

// ---------------- launcher ----------------
extern "C" void kernel_launch(void* const* d_in, const int* in_sizes, int n_in,
                              void* d_out, int out_size, void* d_ws, size_t ws_size,
                              hipStream_t stream) {
    const float* x   = (const float*)d_in[0];
    const int*   ei  = (const int*)d_in[1];   // [2,E] int32 (JAX x64 disabled)
    const float* Wp1 = (const float*)d_in[2],  *bp1 = (const float*)d_in[3];
    const float* Wp2 = (const float*)d_in[4],  *bp2 = (const float*)d_in[5];
    const float* Wp3 = (const float*)d_in[6],  *bp3 = (const float*)d_in[7];
    const float* Wv1 = (const float*)d_in[8],  *bv1 = (const float*)d_in[9];
    const float* Wv2 = (const float*)d_in[10], *bv2 = (const float*)d_in[11];
    const float* Wv3 = (const float*)d_in[12], *bv3 = (const float*)d_in[13];
    float* out_logits = (float*)d_out;
    float* out_v = (float*)d_out + (size_t)NN * 8;

    char* w = (char*)d_ws;
    auto alloc = [&](size_t bytes) {
        char* p = w;
        w += (bytes + 255) & ~(size_t)255;
        return p;
    };
    int*   cnt    = (int*)alloc(NN * 4);
    int*   fill   = (int*)alloc(NN * 4);
    int*   rowptr = (int*)alloc(NN * 4);
    int*   bsum   = (int*)alloc(256 * 4);
    int*   boff   = (int*)alloc(256 * 4);
    float* dinv   = (float*)alloc(NN * 4);
    int*   col    = (int*)alloc(NE * 4);
    float* val    = (float*)alloc(NE * 4);
    float* f0     = (float*)alloc((size_t)NN * 128 * 4);
    float* f1     = (float*)alloc((size_t)NN * 128 * 4);
    float* f2     = (float*)alloc((size_t)NN * 128 * 4);
    // total ~83 MB of d_ws

    const int NB = (NN + 255) / 256;   // 196
    const int EB = (NE + 255) / 256;
    const int GB = (NN + 127) / 128;   // 391
    const int AB = NN / 4;             // 12500 (N divisible by 4)

    // graph build (per launch; buffers re-zeroed every call -> deterministic work)
    k_zero<<<NB, 256, 0, stream>>>(cnt, fill);
    k_count<<<EB, 256, 0, stream>>>(ei, cnt);
    k_dinv<<<NB, 256, 0, stream>>>(cnt, dinv);
    k_scan1<<<NB, 256, 0, stream>>>(cnt, rowptr, bsum);
    k_scan2<<<1, 256, 0, stream>>>(bsum, boff, NB);
    k_scan3<<<NB, 256, 0, stream>>>(rowptr, boff);
    k_fill<<<EB, 256, 0, stream>>>(ei, rowptr, fill, dinv, col, val);

    // policy branch
    k_gemm128<<<GB, 256, 0, stream>>>(x, Wp1, f0, NN);
    k_agg128<<<AB, 256, 0, stream>>>(f0, f1, bp1, dinv, rowptr, cnt, col, val, 1);
    k_gemm128<<<GB, 256, 0, stream>>>(f1, Wp2, f0, NN);
    k_agg128<<<AB, 256, 0, stream>>>(f0, f2, bp2, dinv, rowptr, cnt, col, val, 1);
    k_gemm_small<8><<<NB, 256, 0, stream>>>(f2, Wp3, f0);
    k_agg_small<8><<<NB, 256, 0, stream>>>(f0, out_logits, bp3, dinv, rowptr, cnt, col, val);

    // value branch
    k_gemm128<<<GB, 256, 0, stream>>>(x, Wv1, f0, NN);
    k_agg128<<<AB, 256, 0, stream>>>(f0, f1, bv1, dinv, rowptr, cnt, col, val, 1);
    k_gemm128<<<GB, 256, 0, stream>>>(f1, Wv2, f0, NN);
    k_agg128<<<AB, 256, 0, stream>>>(f0, f2, bv2, dinv, rowptr, cnt, col, val, 1);
    k_gemm_small<1><<<NB, 256, 0, stream>>>(f2, Wv3, f0);
    k_agg_small<1><<<NB, 256, 0, stream>>>(f0, out_v, bv3, dinv, rowptr, cnt, col, val);
}

// Round 2
// 364.662 us; speedup vs baseline: 1.2328x; 1.2328x over previous
//
#include <hip/hip_runtime.h>

#define NN 50000
#define NE 600000

typedef unsigned short ushort_t;
typedef ushort_t ushortx8 __attribute__((ext_vector_type(8)));
typedef ushort_t ushortx4 __attribute__((ext_vector_type(4)));

__device__ __forceinline__ float bf2f(ushort_t u) {
    union { unsigned int i; float f; } c;
    c.i = ((unsigned int)u) << 16;
    return c.f;
}
__device__ __forceinline__ ushort_t f2bf(float f) {
    union { float f; unsigned int i; } c;
    c.f = f;
    unsigned int u = c.i;
    unsigned int r = u + 0x7FFFu + ((u >> 16) & 1u);   // RNE
    return (ushort_t)(r >> 16);
}

// ---------------- graph build ----------------

__global__ void k_zero(int* cnt, int* fill) {
    int i = blockIdx.x * 256 + threadIdx.x;
    if (i < NN) { cnt[i] = 0; fill[i] = 0; }
}

__global__ void k_count(const int* __restrict__ ei, int* __restrict__ cnt) {
    int e = blockIdx.x * 256 + threadIdx.x;
    if (e < NE) atomicAdd(&cnt[ei[NE + e]], 1);
}

__global__ void k_dinv(const int* __restrict__ cnt, float* __restrict__ dinv) {
    int i = blockIdx.x * 256 + threadIdx.x;
    if (i < NN) dinv[i] = rsqrtf(1.0f + (float)cnt[i]);
}

__global__ void k_scan1(const int* __restrict__ cnt, int* __restrict__ rowptr,
                        int* __restrict__ bsum) {
    __shared__ int s[256];
    int t = threadIdx.x;
    int i = blockIdx.x * 256 + t;
    int v = (i < NN) ? cnt[i] : 0;
    s[t] = v;
    __syncthreads();
    for (int d = 1; d < 256; d <<= 1) {
        int tmp = (t >= d) ? s[t - d] : 0;
        __syncthreads();
        s[t] += tmp;
        __syncthreads();
    }
    if (i < NN) rowptr[i] = s[t] - v;
    if (t == 255) bsum[blockIdx.x] = s[255];
}

__global__ void k_scan2(int* __restrict__ bsum, int* __restrict__ boff, int nb) {
    __shared__ int s[256];
    int t = threadIdx.x;
    int v = (t < nb) ? bsum[t] : 0;
    s[t] = v;
    __syncthreads();
    for (int d = 1; d < 256; d <<= 1) {
        int tmp = (t >= d) ? s[t - d] : 0;
        __syncthreads();
        s[t] += tmp;
        __syncthreads();
    }
    boff[t] = s[t] - v;
}

__global__ void k_scan3(int* __restrict__ rowptr, const int* __restrict__ boff) {
    int i = blockIdx.x * 256 + threadIdx.x;
    if (i < NN) rowptr[i] += boff[blockIdx.x];
}

__global__ void k_fill(const int* __restrict__ ei, const int* __restrict__ rowptr,
                       int* __restrict__ fill, const float* __restrict__ dinv,
                       int* __restrict__ col, float* __restrict__ val) {
    int e = blockIdx.x * 256 + threadIdx.x;
    if (e < NE) {
        int s = ei[e];
        int d = ei[NE + e];
        int pos = rowptr[d] + atomicAdd(&fill[d], 1);
        col[pos] = s;
        val[pos] = dinv[s] * dinv[d];
    }
}

// ---------------- GEMM [N,128] @ [128,128], fp32 in, bf16 out ----------------
__global__ __launch_bounds__(256, 2) void k_gemm128(const float* __restrict__ X,
                                                    const float* __restrict__ W,
                                                    ushort_t* __restrict__ Hb, int nrows) {
    __shared__ float Wl[128 * 128];
    __shared__ float xT[16 * 132];
    int t = threadIdx.x;

    const float4* W4 = (const float4*)W;
    float4* Wl4 = (float4*)Wl;
#pragma unroll
    for (int j = 0; j < 16; ++j) Wl4[t + j * 256] = W4[t + j * 256];

    int rowBase = blockIdx.x * 128;
    int rg = t >> 4, cg = t & 15;
    int r0 = rg * 8;
    int ca = cg * 4;
    int cb = 64 + cg * 4;
    int chunk = t & 3, rr = t >> 2;

    float acc[8][8] = {};

    for (int p = 0; p < 8; ++p) {
        int k0 = p * 16;
#pragma unroll
        for (int ps = 0; ps < 2; ++ps) {
            int r = rr + ps * 64;
            int gr = rowBase + r;
            float4 g = {0.f, 0.f, 0.f, 0.f};
            if (gr < nrows) g = ((const float4*)X)[gr * 32 + (k0 >> 2) + chunk];
            xT[(chunk * 4 + 0) * 132 + r] = g.x;
            xT[(chunk * 4 + 1) * 132 + r] = g.y;
            xT[(chunk * 4 + 2) * 132 + r] = g.z;
            xT[(chunk * 4 + 3) * 132 + r] = g.w;
        }
        __syncthreads();
#pragma unroll
        for (int kk = 0; kk < 16; ++kk) {
            int krow = k0 + kk;
            float4 xa = *(const float4*)&xT[kk * 132 + r0];
            float4 xb = *(const float4*)&xT[kk * 132 + r0 + 4];
            float4 wa = *(const float4*)&Wl[krow * 128 + ca];
            float4 wb = *(const float4*)&Wl[krow * 128 + cb];
            float xs[8] = {xa.x, xa.y, xa.z, xa.w, xb.x, xb.y, xb.z, xb.w};
            float ws[8] = {wa.x, wa.y, wa.z, wa.w, wb.x, wb.y, wb.z, wb.w};
#pragma unroll
            for (int i = 0; i < 8; ++i)
#pragma unroll
                for (int j = 0; j < 8; ++j) acc[i][j] += xs[i] * ws[j];
        }
        __syncthreads();
    }

#pragma unroll
    for (int i = 0; i < 8; ++i) {
        int gr = rowBase + r0 + i;
        if (gr < nrows) {
            ushortx4 pa = {f2bf(acc[i][0]), f2bf(acc[i][1]), f2bf(acc[i][2]), f2bf(acc[i][3])};
            ushortx4 pb = {f2bf(acc[i][4]), f2bf(acc[i][5]), f2bf(acc[i][6]), f2bf(acc[i][7])};
            ((ushortx4*)Hb)[gr * 32 + cg] = pa;
            ((ushortx4*)Hb)[gr * 32 + 16 + cg] = pb;
        }
    }
}

// ---------------- small GEMM [N,128] @ [128,CO], fp32 ----------------
template <int CO>
__global__ void k_gemm_small(const float* __restrict__ X, const float* __restrict__ W,
                             float* __restrict__ C) {
    __shared__ float Wt[CO * 128];
    int t = threadIdx.x;
    for (int j = t; j < 128 * CO; j += 256) {
        int k = j / CO, c = j % CO;
        Wt[c * 128 + k] = W[j];
    }
    __syncthreads();
    int row = blockIdx.x * 256 + t;
    if (row >= NN) return;
    const float4* X4 = (const float4*)X;
    float acc[CO] = {};
#pragma unroll 4
    for (int kc = 0; kc < 32; ++kc) {
        float4 xv = X4[row * 32 + kc];
#pragma unroll
        for (int c = 0; c < CO; ++c) {
            acc[c] += xv.x * Wt[c * 128 + kc * 4 + 0] + xv.y * Wt[c * 128 + kc * 4 + 1] +
                      xv.z * Wt[c * 128 + kc * 4 + 2] + xv.w * Wt[c * 128 + kc * 4 + 3];
        }
    }
#pragma unroll
    for (int c = 0; c < CO; ++c) C[row * CO + c] = acc[c] + 0.0f;
}

// ---------------- aggregation, 128 features, bf16 gather -> fp32 out ----------------
// one wave per node; 4 quarter-waves (16 lanes x 16B) x 2-deep unroll = 8 loads in flight.
__global__ __launch_bounds__(256) void k_agg128b(const ushort_t* __restrict__ H,
                                                 float* __restrict__ OUT,
                                                 const float* __restrict__ bias,
                                                 const float* __restrict__ dinv,
                                                 const int* __restrict__ rowptr,
                                                 const int* __restrict__ cnt,
                                                 const int* __restrict__ col,
                                                 const float* __restrict__ val, int relu) {
    int wv = threadIdx.x >> 6;
    int l = threadIdx.x & 63;
    int i = blockIdx.x * 4 + wv;
    if (i >= NN) return;
    int q = l >> 4, lf = l & 15;
    const ushortx8* H8 = (const ushortx8*)H;   // row = 16 chunks of 8 bf16

    float a0[8] = {}, a1[8] = {};
    if (q == 0) {   // self loop, weight dinv^2
        float w = dinv[i];
        w *= w;
        ushortx8 h = H8[i * 16 + lf];
#pragma unroll
        for (int k = 0; k < 8; ++k) a0[k] = w * bf2f(h[k]);
    }
    int st = rowptr[i];
    int n = cnt[i];
    int j = q;
    for (; j + 4 < n; j += 8) {
        int e0 = st + j, e1 = e0 + 4;
        int s0 = col[e0], s1 = col[e1];
        float w0 = val[e0], w1 = val[e1];
        ushortx8 h0 = H8[s0 * 16 + lf];
        ushortx8 h1 = H8[s1 * 16 + lf];
#pragma unroll
        for (int k = 0; k < 8; ++k) a0[k] += w0 * bf2f(h0[k]);
#pragma unroll
        for (int k = 0; k < 8; ++k) a1[k] += w1 * bf2f(h1[k]);
    }
    if (j < n) {
        int e0 = st + j;
        int s0 = col[e0];
        float w0 = val[e0];
        ushortx8 h0 = H8[s0 * 16 + lf];
#pragma unroll
        for (int k = 0; k < 8; ++k) a0[k] += w0 * bf2f(h0[k]);
    }
#pragma unroll
    for (int k = 0; k < 8; ++k) a0[k] += a1[k];
#pragma unroll
    for (int k = 0; k < 8; ++k) {
        a0[k] += __shfl_xor(a0[k], 16, 64);
        a0[k] += __shfl_xor(a0[k], 32, 64);
    }
    if (q == 0) {
        float4 b0 = ((const float4*)bias)[lf * 2];
        float4 b1 = ((const float4*)bias)[lf * 2 + 1];
        float r[8];
        r[0] = a0[0] + b0.x; r[1] = a0[1] + b0.y; r[2] = a0[2] + b0.z; r[3] = a0[3] + b0.w;
        r[4] = a0[4] + b1.x; r[5] = a0[5] + b1.y; r[6] = a0[6] + b1.z; r[7] = a0[7] + b1.w;
        if (relu) {
#pragma unroll
            for (int k = 0; k < 8; ++k) r[k] = fmaxf(r[k], 0.f);
        }
        float4 o0 = {r[0], r[1], r[2], r[3]};
        float4 o1 = {r[4], r[5], r[6], r[7]};
        ((float4*)OUT)[i * 32 + lf * 2] = o0;
        ((float4*)OUT)[i * 32 + lf * 2 + 1] = o1;
    }
}

// ---------------- aggregation, CO features (8 or 1), fp32, no relu ----------------
template <int CO>
__global__ void k_agg_small(const float* __restrict__ H, float* __restrict__ OUT,
                            const float* __restrict__ bias, const float* __restrict__ dinv,
                            const int* __restrict__ rowptr, const int* __restrict__ cnt,
                            const int* __restrict__ col, const float* __restrict__ val) {
    int i = blockIdx.x * 256 + threadIdx.x;
    if (i >= NN) return;
    float di = dinv[i];
    float w0 = di * di;
    float acc[CO];
#pragma unroll
    for (int c = 0; c < CO; ++c) acc[c] = w0 * H[i * CO + c];
    int st = rowptr[i];
    int n = cnt[i];
    for (int j = 0; j < n; ++j) {
        int e = st + j;
        int s = col[e];
        float w = val[e];
#pragma unroll
        for (int c = 0; c < CO; ++c) acc[c] += w * H[s * CO + c];
    }
#pragma unroll
    for (int c = 0; c < CO; ++c) OUT[i * CO + c] = acc[c] + bias[c];
}

// ---------------- launcher ----------------
extern "C" void kernel_launch(void* const* d_in, const int* in_sizes, int n_in,
                              void* d_out, int out_size, void* d_ws, size_t ws_size,
                              hipStream_t stream) {
    const float* x   = (const float*)d_in[0];
    const int*   ei  = (const int*)d_in[1];
    const float* Wp1 = (const float*)d_in[2],  *bp1 = (const float*)d_in[3];
    const float* Wp2 = (const float*)d_in[4],  *bp2 = (const float*)d_in[5];
    const float* Wp3 = (const float*)d_in[6],  *bp3 = (const float*)d_in[7];
    const float* Wv1 = (const float*)d_in[8],  *bv1 = (const float*)d_in[9];
    const float* Wv2 = (const float*)d_in[10], *bv2 = (const float*)d_in[11];
    const float* Wv3 = (const float*)d_in[12], *bv3 = (const float*)d_in[13];
    float* out_logits = (float*)d_out;
    float* out_v = (float*)d_out + (size_t)NN * 8;

    char* w = (char*)d_ws;
    auto alloc = [&](size_t bytes) {
        char* p = w;
        w += (bytes + 255) & ~(size_t)255;
        return p;
    };
    int*     cnt    = (int*)alloc(NN * 4);
    int*     fill   = (int*)alloc(NN * 4);
    int*     rowptr = (int*)alloc(NN * 4);
    int*     bsum   = (int*)alloc(256 * 4);
    int*     boff   = (int*)alloc(256 * 4);
    float*   dinv   = (float*)alloc(NN * 4);
    int*     col    = (int*)alloc(NE * 4);
    float*   val    = (float*)alloc(NE * 4);
    ushort_t* Hb    = (ushort_t*)alloc((size_t)NN * 128 * 2);   // bf16 conv outputs
    float*   f1     = (float*)alloc((size_t)NN * 128 * 4);      // fp32 agg outputs
    float*   f2     = (float*)alloc((size_t)NN * 128 * 4);
    float*   fs     = (float*)alloc((size_t)NN * 8 * 4);        // small intermediates
    // total ~71 MB of d_ws

    const int NB = (NN + 255) / 256;
    const int EB = (NE + 255) / 256;
    const int GB = (NN + 127) / 128;
    const int AB = NN / 4;

    k_zero<<<NB, 256, 0, stream>>>(cnt, fill);
    k_count<<<EB, 256, 0, stream>>>(ei, cnt);
    k_dinv<<<NB, 256, 0, stream>>>(cnt, dinv);
    k_scan1<<<NB, 256, 0, stream>>>(cnt, rowptr, bsum);
    k_scan2<<<1, 256, 0, stream>>>(bsum, boff, NB);
    k_scan3<<<NB, 256, 0, stream>>>(rowptr, boff);
    k_fill<<<EB, 256, 0, stream>>>(ei, rowptr, fill, dinv, col, val);

    // policy branch
    k_gemm128<<<GB, 256, 0, stream>>>(x, Wp1, Hb, NN);
    k_agg128b<<<AB, 256, 0, stream>>>(Hb, f1, bp1, dinv, rowptr, cnt, col, val, 1);
    k_gemm128<<<GB, 256, 0, stream>>>(f1, Wp2, Hb, NN);
    k_agg128b<<<AB, 256, 0, stream>>>(Hb, f2, bp2, dinv, rowptr, cnt, col, val, 1);
    k_gemm_small<8><<<NB, 256, 0, stream>>>(f2, Wp3, fs);
    k_agg_small<8><<<NB, 256, 0, stream>>>(fs, out_logits, bp3, dinv, rowptr, cnt, col, val);

    // value branch
    k_gemm128<<<GB, 256, 0, stream>>>(x, Wv1, Hb, NN);
    k_agg128b<<<AB, 256, 0, stream>>>(Hb, f1, bv1, dinv, rowptr, cnt, col, val, 1);
    k_gemm128<<<GB, 256, 0, stream>>>(f1, Wv2, Hb, NN);
    k_agg128b<<<AB, 256, 0, stream>>>(Hb, f2, bv2, dinv, rowptr, cnt, col, val, 1);
    k_gemm_small<1><<<NB, 256, 0, stream>>>(f2, Wv3, fs);
    k_agg_small<1><<<NB, 256, 0, stream>>>(fs, out_v, bv3, dinv, rowptr, cnt, col, val);
}

// Round 3
// 259.902 us; speedup vs baseline: 1.7296x; 1.4031x over previous
//
#include <hip/hip_runtime.h>

#define NN 50000
#define NE 600000

typedef unsigned short ushort_t;
typedef ushort_t ushortx8 __attribute__((ext_vector_type(8)));
typedef ushort_t ushortx4 __attribute__((ext_vector_type(4)));
typedef short bf16x8 __attribute__((ext_vector_type(8)));
typedef float f32x4 __attribute__((ext_vector_type(4)));

__device__ __forceinline__ float bf2f(ushort_t u) {
    union { unsigned int i; float f; } c;
    c.i = ((unsigned int)u) << 16;
    return c.f;
}
__device__ __forceinline__ ushort_t f2bf(float f) {
    union { float f; unsigned int i; } c;
    c.f = f;
    unsigned int u = c.i;
    unsigned int r = u + 0x7FFFu + ((u >> 16) & 1u);   // RNE
    return (ushort_t)(r >> 16);
}

// ---------------- graph build ----------------

__global__ void k_zero(int* cnt, int* fill) {
    int i = blockIdx.x * 256 + threadIdx.x;
    if (i < NN) { cnt[i] = 0; fill[i] = 0; }
}

__global__ void k_count(const int* __restrict__ ei, int* __restrict__ cnt) {
    int e = blockIdx.x * 256 + threadIdx.x;
    if (e < NE) atomicAdd(&cnt[ei[NE + e]], 1);
}

__global__ void k_dinv(const int* __restrict__ cnt, float* __restrict__ dinv) {
    int i = blockIdx.x * 256 + threadIdx.x;
    if (i < NN) dinv[i] = rsqrtf(1.0f + (float)cnt[i]);
}

__global__ void k_scan1(const int* __restrict__ cnt, int* __restrict__ rowptr,
                        int* __restrict__ bsum) {
    __shared__ int s[256];
    int t = threadIdx.x;
    int i = blockIdx.x * 256 + t;
    int v = (i < NN) ? cnt[i] : 0;
    s[t] = v;
    __syncthreads();
    for (int d = 1; d < 256; d <<= 1) {
        int tmp = (t >= d) ? s[t - d] : 0;
        __syncthreads();
        s[t] += tmp;
        __syncthreads();
    }
    if (i < NN) rowptr[i] = s[t] - v;
    if (t == 255) bsum[blockIdx.x] = s[255];
}

__global__ void k_scan2(int* __restrict__ bsum, int* __restrict__ boff, int nb) {
    __shared__ int s[256];
    int t = threadIdx.x;
    int v = (t < nb) ? bsum[t] : 0;
    s[t] = v;
    __syncthreads();
    for (int d = 1; d < 256; d <<= 1) {
        int tmp = (t >= d) ? s[t - d] : 0;
        __syncthreads();
        s[t] += tmp;
        __syncthreads();
    }
    boff[t] = s[t] - v;
}

__global__ void k_scan3(int* __restrict__ rowptr, const int* __restrict__ boff) {
    int i = blockIdx.x * 256 + threadIdx.x;
    if (i < NN) rowptr[i] += boff[blockIdx.x];
}

__global__ void k_fill(const int* __restrict__ ei, const int* __restrict__ rowptr,
                       int* __restrict__ fill, const float* __restrict__ dinv,
                       int* __restrict__ col, float* __restrict__ val) {
    int e = blockIdx.x * 256 + threadIdx.x;
    if (e < NE) {
        int s = ei[e];
        int d = ei[NE + e];
        int pos = rowptr[d] + atomicAdd(&fill[d], 1);
        col[pos] = s;
        val[pos] = dinv[s] * dinv[d];
    }
}

// ---------------- weight prep: transpose + bf16 ----------------
// Wt[n][k] = W[k][n]
__global__ void k_prep_w(const float* __restrict__ Wp1, const float* __restrict__ Wv1,
                         const float* __restrict__ Wp2, const float* __restrict__ Wv2,
                         ushort_t* __restrict__ Wt1, ushort_t* __restrict__ Wt2p,
                         ushort_t* __restrict__ Wt2v) {
    int b = blockIdx.x, t = threadIdx.x;
    if (b < 128) {
        int idx = b * 256 + t;
        int n = idx >> 7, k = idx & 127;
        float v = (n < 128) ? Wp1[k * 128 + n] : Wv1[k * 128 + (n - 128)];
        Wt1[n * 128 + k] = f2bf(v);
    } else if (b < 192) {
        int idx = (b - 128) * 256 + t;
        int n = idx >> 7, k = idx & 127;
        Wt2p[n * 128 + k] = f2bf(Wp2[k * 128 + n]);
    } else {
        int idx = (b - 192) * 256 + t;
        int n = idx >> 7, k = idx & 127;
        Wt2v[n * 128 + k] = f2bf(Wv2[k * 128 + n]);
    }
}

// ---------------- x -> bf16 ----------------
__global__ void k_xbf(const float* __restrict__ X, ushort_t* __restrict__ XB) {
    size_t i = (size_t)blockIdx.x * 256 + threadIdx.x;   // one 8-elem chunk
    const float4* X4 = (const float4*)X;
    float4 a = X4[i * 2], b = X4[i * 2 + 1];
    ushortx8 o = {f2bf(a.x), f2bf(a.y), f2bf(a.z), f2bf(a.w),
                  f2bf(b.x), f2bf(b.y), f2bf(b.z), f2bf(b.w)};
    ((ushortx8*)XB)[i] = o;
}

// ---------------- MFMA GEMM: C[:, c_off:c_off+NT*16] = A[:, koff:koff+128] @ W ----------
// A bf16 (a_stride elems/row), Wt bf16 [NT*16][128] (n-major, transposed), C bf16.
// Workgroup: 4 waves, 64 rows; wave = 16-row strip. 16x16x32 MFMA,
// frag k-map: lane g=(l>>4) holds k = g*8 + j (contiguous 8 -> one b128).
template <int NT>
__global__ __launch_bounds__(256, 2) void k_gemm_mfma(const ushort_t* __restrict__ A,
                                                      int a_stride, int a_koff,
                                                      const ushort_t* __restrict__ Wt,
                                                      ushort_t* __restrict__ C, int c_stride,
                                                      int c_off, int nrows) {
    __shared__ ushort_t Wl[NT * 16 * 128];
    __shared__ ushort_t Al[64 * 128];
    int t = threadIdx.x;

    const ushortx8* Wg = (const ushortx8*)Wt;
#pragma unroll
    for (int i = 0; i < NT; ++i) {
        int c = i * 256 + t;
        int row = c >> 4, slot = c & 15;
        int db = row * 256 + ((slot * 16) ^ ((row & 7) << 4));
        *(ushortx8*)((char*)Wl + db) = Wg[c];
    }
    int rb = blockIdx.x * 64;
#pragma unroll
    for (int i = 0; i < 4; ++i) {
        int c = i * 256 + t;
        int row = c >> 4, slot = c & 15;
        int gr = rb + row;
        ushortx8 v = {0, 0, 0, 0, 0, 0, 0, 0};
        if (gr < nrows) v = *(const ushortx8*)(A + (size_t)gr * a_stride + a_koff + slot * 8);
        int db = row * 256 + ((slot * 16) ^ ((row & 7) << 4));
        *(ushortx8*)((char*)Al + db) = v;
    }
    __syncthreads();

    int w = t >> 6, l = t & 63, m = l & 15, g = l >> 4;
    int r0 = rb + w * 16;
    if (r0 >= nrows) return;   // whole-strip OOB (nrows % 16 == 0); no barriers after

    const char* Ab = (const char*)Al + (w * 16 + m) * 256;
    int sw = (m & 7) << 4;
    bf16x8 af[4];
#pragma unroll
    for (int kk = 0; kk < 4; ++kk)
        af[kk] = *(const bf16x8*)(Ab + ((kk * 64 + g * 16) ^ sw));

    f32x4 acc[NT];
#pragma unroll
    for (int nt = 0; nt < NT; ++nt) acc[nt] = (f32x4){0.f, 0.f, 0.f, 0.f};

#pragma unroll
    for (int nt = 0; nt < NT; ++nt) {
        const char* Wb = (const char*)Wl + (nt * 16 + m) * 256;
#pragma unroll
        for (int kk = 0; kk < 4; ++kk) {
            bf16x8 wf = *(const bf16x8*)(Wb + ((kk * 64 + g * 16) ^ sw));
            // W as A-operand => lane holds C[r0+m][c_off + nt*16 + g*4 + j]
            acc[nt] = __builtin_amdgcn_mfma_f32_16x16x32_bf16(wf, af[kk], acc[nt], 0, 0, 0);
        }
    }
#pragma unroll
    for (int nt = 0; nt < NT; ++nt) {
        ushortx4 o = {f2bf(acc[nt][0]), f2bf(acc[nt][1]), f2bf(acc[nt][2]), f2bf(acc[nt][3])};
        *(ushortx4*)(C + (size_t)(r0 + m) * c_stride + c_off + nt * 16 + g * 4) = o;
    }
}

// ---------------- fused aggregation, 256 features, bf16 gather ----------------
// wave per node; half-wave (32 lanes x 16B) covers a 512B row; 4-deep edge unroll.
__global__ __launch_bounds__(256) void k_agg256(const ushort_t* __restrict__ H,
                                                void* __restrict__ OUTv,
                                                const float* __restrict__ b_lo,
                                                const float* __restrict__ b_hi,
                                                const float* __restrict__ dinv,
                                                const int* __restrict__ rowptr,
                                                const int* __restrict__ cnt,
                                                const int* __restrict__ col,
                                                const float* __restrict__ val, int out_bf16) {
    int wv = threadIdx.x >> 6;
    int l = threadIdx.x & 63;
    int i = blockIdx.x * 4 + wv;
    if (i >= NN) return;
    int h = l >> 5, q = l & 31;
    const ushortx8* H8 = (const ushortx8*)H;

    float a0[8] = {}, a1[8] = {};
    float di = dinv[i];
    if (h == 0) {
        float ws = di * di;
        ushortx8 hv = H8[(size_t)i * 32 + q];
#pragma unroll
        for (int k = 0; k < 8; ++k) a0[k] = ws * bf2f(hv[k]);
    }
    int st = rowptr[i];
    int n = cnt[i];
    int j = h;
    for (; j + 6 < n; j += 8) {
        int e0 = st + j, e1 = st + j + 2, e2 = st + j + 4, e3 = st + j + 6;
        int s0 = col[e0], s1 = col[e1], s2 = col[e2], s3 = col[e3];
        float w0 = val[e0], w1 = val[e1], w2 = val[e2], w3 = val[e3];
        ushortx8 h0 = H8[(size_t)s0 * 32 + q];
        ushortx8 h1 = H8[(size_t)s1 * 32 + q];
        ushortx8 h2 = H8[(size_t)s2 * 32 + q];
        ushortx8 h3 = H8[(size_t)s3 * 32 + q];
#pragma unroll
        for (int k = 0; k < 8; ++k) a0[k] += w0 * bf2f(h0[k]);
#pragma unroll
        for (int k = 0; k < 8; ++k) a1[k] += w1 * bf2f(h1[k]);
#pragma unroll
        for (int k = 0; k < 8; ++k) a0[k] += w2 * bf2f(h2[k]);
#pragma unroll
        for (int k = 0; k < 8; ++k) a1[k] += w3 * bf2f(h3[k]);
    }
    for (; j < n; j += 2) {
        int e0 = st + j;
        int s0 = col[e0];
        float w0 = val[e0];
        ushortx8 h0 = H8[(size_t)s0 * 32 + q];
#pragma unroll
        for (int k = 0; k < 8; ++k) a0[k] += w0 * bf2f(h0[k]);
    }
#pragma unroll
    for (int k = 0; k < 8; ++k) a0[k] += a1[k];
#pragma unroll
    for (int k = 0; k < 8; ++k) a0[k] += __shfl_xor(a0[k], 32, 64);

    if (h == 0) {
        const float* bb = (q < 16) ? (b_lo + q * 8) : (b_hi + (q - 16) * 8);
        float4 b0 = *(const float4*)bb;
        float4 b1 = *(const float4*)(bb + 4);
        float r[8];
        r[0] = fmaxf(a0[0] + b0.x, 0.f); r[1] = fmaxf(a0[1] + b0.y, 0.f);
        r[2] = fmaxf(a0[2] + b0.z, 0.f); r[3] = fmaxf(a0[3] + b0.w, 0.f);
        r[4] = fmaxf(a0[4] + b1.x, 0.f); r[5] = fmaxf(a0[5] + b1.y, 0.f);
        r[6] = fmaxf(a0[6] + b1.z, 0.f); r[7] = fmaxf(a0[7] + b1.w, 0.f);
        if (out_bf16) {
            ushortx8 o = {f2bf(r[0]), f2bf(r[1]), f2bf(r[2]), f2bf(r[3]),
                          f2bf(r[4]), f2bf(r[5]), f2bf(r[6]), f2bf(r[7])};
            ((ushortx8*)OUTv)[(size_t)i * 32 + q] = o;
        } else {
            float4 o0 = {r[0], r[1], r[2], r[3]};
            float4 o1 = {r[4], r[5], r[6], r[7]};
            ((float4*)OUTv)[(size_t)i * 64 + q * 2] = o0;
            ((float4*)OUTv)[(size_t)i * 64 + q * 2 + 1] = o1;
        }
    }
}

// ---------------- fused small GEMM: fs[:,0:8] = f2[:,0:128]@Wp3 ; fs[:,8] = f2[:,128:256]@Wv3
__global__ __launch_bounds__(256) void k_small(const float* __restrict__ F2,
                                               const float* __restrict__ Wp3,
                                               const float* __restrict__ Wv3,
                                               float* __restrict__ FS) {
    __shared__ float Wp[8 * 128];
    __shared__ float Wv[128];
    int t = threadIdx.x;
    for (int j = t; j < 1024; j += 256) {
        int k = j >> 3, c = j & 7;
        Wp[c * 128 + k] = Wp3[j];
    }
    if (t < 128) Wv[t] = Wv3[t];
    __syncthreads();
    int row = blockIdx.x * 256 + t;
    if (row >= NN) return;
    const float4* F4 = (const float4*)F2;
    size_t base = (size_t)row * 64;
    float acc[9] = {};
#pragma unroll 4
    for (int kc = 0; kc < 32; ++kc) {
        float4 p = F4[base + kc];
        float4 v = F4[base + 32 + kc];
#pragma unroll
        for (int c = 0; c < 8; ++c) {
            const float* wc = &Wp[c * 128 + kc * 4];
            acc[c] += p.x * wc[0] + p.y * wc[1] + p.z * wc[2] + p.w * wc[3];
        }
        const float* wv = &Wv[kc * 4];
        acc[8] += v.x * wv[0] + v.y * wv[1] + v.z * wv[2] + v.w * wv[3];
    }
    float4* FSo = (float4*)(FS + (size_t)row * 12);
    float4 o0 = {acc[0], acc[1], acc[2], acc[3]};
    float4 o1 = {acc[4], acc[5], acc[6], acc[7]};
    float4 o2 = {acc[8], 0.f, 0.f, 0.f};
    FSo[0] = o0; FSo[1] = o1; FSo[2] = o2;
}

// ---------------- final fused aggregation (8 logits + 1 value) ----------------
__global__ void k_agg9(const float* __restrict__ FS, float* __restrict__ out_logits,
                       float* __restrict__ out_v, const float* __restrict__ bp3,
                       const float* __restrict__ bv3, const float* __restrict__ dinv,
                       const int* __restrict__ rowptr, const int* __restrict__ cnt,
                       const int* __restrict__ col, const float* __restrict__ val) {
    int i = blockIdx.x * 256 + threadIdx.x;
    if (i >= NN) return;
    float di = dinv[i];
    float w0 = di * di;
    const float4* F = (const float4*)FS;
    size_t b0 = (size_t)i * 3;
    float4 x0 = F[b0], x1 = F[b0 + 1], x2 = F[b0 + 2];
    float a[9];
    a[0] = w0 * x0.x; a[1] = w0 * x0.y; a[2] = w0 * x0.z; a[3] = w0 * x0.w;
    a[4] = w0 * x1.x; a[5] = w0 * x1.y; a[6] = w0 * x1.z; a[7] = w0 * x1.w;
    a[8] = w0 * x2.x;
    int st = rowptr[i];
    int n = cnt[i];
    for (int j = 0; j < n; ++j) {
        int e = st + j;
        int s = col[e];
        float w = val[e];
        size_t sb = (size_t)s * 3;
        float4 y0 = F[sb], y1 = F[sb + 1], y2 = F[sb + 2];
        a[0] += w * y0.x; a[1] += w * y0.y; a[2] += w * y0.z; a[3] += w * y0.w;
        a[4] += w * y1.x; a[5] += w * y1.y; a[6] += w * y1.z; a[7] += w * y1.w;
        a[8] += w * y2.x;
    }
    float4 bpa = *(const float4*)bp3;
    float4 bpb = *(const float4*)(bp3 + 4);
    float4 o0 = {a[0] + bpa.x, a[1] + bpa.y, a[2] + bpa.z, a[3] + bpa.w};
    float4 o1 = {a[4] + bpb.x, a[5] + bpb.y, a[6] + bpb.z, a[7] + bpb.w};
    ((float4*)out_logits)[(size_t)i * 2] = o0;
    ((float4*)out_logits)[(size_t)i * 2 + 1] = o1;
    out_v[i] = a[8] + bv3[0];
}

// ---------------- launcher ----------------
extern "C" void kernel_launch(void* const* d_in, const int* in_sizes, int n_in,
                              void* d_out, int out_size, void* d_ws, size_t ws_size,
                              hipStream_t stream) {
    const float* x   = (const float*)d_in[0];
    const int*   ei  = (const int*)d_in[1];
    const float* Wp1 = (const float*)d_in[2],  *bp1 = (const float*)d_in[3];
    const float* Wp2 = (const float*)d_in[4],  *bp2 = (const float*)d_in[5];
    const float* Wp3 = (const float*)d_in[6],  *bp3 = (const float*)d_in[7];
    const float* Wv1 = (const float*)d_in[8],  *bv1 = (const float*)d_in[9];
    const float* Wv2 = (const float*)d_in[10], *bv2 = (const float*)d_in[11];
    const float* Wv3 = (const float*)d_in[12], *bv3 = (const float*)d_in[13];
    float* out_logits = (float*)d_out;
    float* out_v = (float*)d_out + (size_t)NN * 8;

    char* w = (char*)d_ws;
    auto alloc = [&](size_t bytes) {
        char* p = w;
        w += (bytes + 255) & ~(size_t)255;
        return p;
    };
    int*      cnt    = (int*)alloc(NN * 4);
    int*      fill   = (int*)alloc(NN * 4);
    int*      rowptr = (int*)alloc(NN * 4);
    int*      bsum   = (int*)alloc(256 * 4);
    int*      boff   = (int*)alloc(256 * 4);
    float*    dinv   = (float*)alloc(NN * 4);
    int*      col    = (int*)alloc(NE * 4);
    float*    val    = (float*)alloc(NE * 4);
    ushort_t* xb     = (ushort_t*)alloc((size_t)NN * 128 * 2);
    ushort_t* Wt1    = (ushort_t*)alloc(256 * 128 * 2);
    ushort_t* Wt2p   = (ushort_t*)alloc(128 * 128 * 2);
    ushort_t* Wt2v   = (ushort_t*)alloc(128 * 128 * 2);
    ushort_t* Hb     = (ushort_t*)alloc((size_t)NN * 256 * 2);   // fused conv out (reused L1/L2)
    ushort_t* f1b    = (ushort_t*)alloc((size_t)NN * 256 * 2);   // agg1 out, bf16
    float*    f2     = (float*)alloc((size_t)NN * 256 * 4);      // agg2 out, fp32
    float*    fs     = (float*)alloc((size_t)NN * 12 * 4);       // small out (9 used)
    // total ~123 MB of 256 MB d_ws

    const int NB = (NN + 255) / 256;   // 196
    const int EB = (NE + 255) / 256;
    const int GB = (NN + 63) / 64;     // 782
    const int AB = NN / 4;             // 12500

    k_zero<<<NB, 256, 0, stream>>>(cnt, fill);
    k_count<<<EB, 256, 0, stream>>>(ei, cnt);
    k_dinv<<<NB, 256, 0, stream>>>(cnt, dinv);
    k_scan1<<<NB, 256, 0, stream>>>(cnt, rowptr, bsum);
    k_scan2<<<1, 256, 0, stream>>>(bsum, boff, NB);
    k_scan3<<<NB, 256, 0, stream>>>(rowptr, boff);
    k_fill<<<EB, 256, 0, stream>>>(ei, rowptr, fill, dinv, col, val);

    k_prep_w<<<256, 256, 0, stream>>>(Wp1, Wv1, Wp2, Wv2, Wt1, Wt2p, Wt2v);
    k_xbf<<<3125, 256, 0, stream>>>(x, xb);

    // layer 1 (policy | value fused into 256 cols)
    k_gemm_mfma<16><<<GB, 256, 0, stream>>>(xb, 128, 0, Wt1, Hb, 256, 0, NN);
    k_agg256<<<AB, 256, 0, stream>>>(Hb, f1b, bp1, bv1, dinv, rowptr, cnt, col, val, 1);
    // layer 2 (block-diagonal)
    k_gemm_mfma<8><<<GB, 256, 0, stream>>>(f1b, 256, 0, Wt2p, Hb, 256, 0, NN);
    k_gemm_mfma<8><<<GB, 256, 0, stream>>>(f1b, 256, 128, Wt2v, Hb, 256, 128, NN);
    k_agg256<<<AB, 256, 0, stream>>>(Hb, f2, bp2, bv2, dinv, rowptr, cnt, col, val, 0);
    // layer 3 (fp32)
    k_small<<<NB, 256, 0, stream>>>(f2, Wp3, Wv3, fs);
    k_agg9<<<NB, 256, 0, stream>>>(fs, out_logits, out_v, bp3, bv3, dinv, rowptr, cnt, col, val);
}

// Round 4
// 234.811 us; speedup vs baseline: 1.9145x; 1.1069x over previous
//
#include <hip/hip_runtime.h>

#define NN 50000
#define NE 600000

typedef unsigned short ushort_t;
typedef ushort_t ushortx8 __attribute__((ext_vector_type(8)));
typedef ushort_t ushortx4 __attribute__((ext_vector_type(4)));
typedef short bf16x8 __attribute__((ext_vector_type(8)));
typedef float f32x4 __attribute__((ext_vector_type(4)));

__device__ __forceinline__ float bf2f(ushort_t u) {
    union { unsigned int i; float f; } c;
    c.i = ((unsigned int)u) << 16;
    return c.f;
}
__device__ __forceinline__ ushort_t f2bf(float f) {
    union { float f; unsigned int i; } c;
    c.f = f;
    unsigned int u = c.i;
    unsigned int r = u + 0x7FFFu + ((u >> 16) & 1u);   // RNE
    return (ushort_t)(r >> 16);
}
__device__ __forceinline__ unsigned cvtpk(float lo, float hi) {
    unsigned r;
    asm("v_cvt_pk_bf16_f32 %0, %1, %2" : "=v"(r) : "v"(lo), "v"(hi));
    return r;
}

// ---------------- graph build ----------------

__global__ void k_count(const int* __restrict__ ei, int* __restrict__ cnt) {
    int e = blockIdx.x * 256 + threadIdx.x;
    if (e < NE) atomicAdd(&cnt[ei[NE + e]], 1);
}

// scan of cnt -> rowptr (exclusive, per-block) + block sums; also dinv
__global__ void k_scan1(const int* __restrict__ cnt, int* __restrict__ rowptr,
                        int* __restrict__ bsum, float* __restrict__ dinv) {
    __shared__ int s[256];
    int t = threadIdx.x;
    int i = blockIdx.x * 256 + t;
    int v = (i < NN) ? cnt[i] : 0;
    if (i < NN) dinv[i] = rsqrtf(1.0f + (float)v);
    s[t] = v;
    __syncthreads();
    for (int d = 1; d < 256; d <<= 1) {
        int tmp = (t >= d) ? s[t - d] : 0;
        __syncthreads();
        s[t] += tmp;
        __syncthreads();
    }
    if (i < NN) rowptr[i] = s[t] - v;
    if (t == 255) bsum[blockIdx.x] = s[255];
}

__global__ void k_scan2(int* __restrict__ bsum, int* __restrict__ boff, int nb) {
    __shared__ int s[256];
    int t = threadIdx.x;
    int v = (t < nb) ? bsum[t] : 0;
    s[t] = v;
    __syncthreads();
    for (int d = 1; d < 256; d <<= 1) {
        int tmp = (t >= d) ? s[t - d] : 0;
        __syncthreads();
        s[t] += tmp;
        __syncthreads();
    }
    boff[t] = s[t] - v;
}

__global__ void k_scan3(int* __restrict__ rowptr, const int* __restrict__ boff) {
    int i = blockIdx.x * 256 + threadIdx.x;
    if (i < NN) rowptr[i] += boff[blockIdx.x];
}

__global__ void k_fill(const int* __restrict__ ei, const int* __restrict__ rowptr,
                       int* __restrict__ fill, const float* __restrict__ dinv,
                       int2* __restrict__ edges) {
    int e = blockIdx.x * 256 + threadIdx.x;
    if (e < NE) {
        int s = ei[e];
        int d = ei[NE + e];
        int pos = rowptr[d] + atomicAdd(&fill[d], 1);
        float w = dinv[s] * dinv[d];
        int2 pr;
        pr.x = s;
        pr.y = __float_as_int(w);
        edges[pos] = pr;
    }
}

// ---------------- weight prep: transpose + bf16 (Wt[n][k] = W[k][n]) ----------------
__global__ void k_prep_w(const float* __restrict__ Wp1, const float* __restrict__ Wv1,
                         const float* __restrict__ Wp2, const float* __restrict__ Wv2,
                         ushort_t* __restrict__ Wt1, ushort_t* __restrict__ Wt2p,
                         ushort_t* __restrict__ Wt2v) {
    int b = blockIdx.x, t = threadIdx.x;
    if (b < 128) {
        int idx = b * 256 + t;
        int n = idx >> 7, k = idx & 127;
        float v = (n < 128) ? Wp1[k * 128 + n] : Wv1[k * 128 + (n - 128)];
        Wt1[n * 128 + k] = f2bf(v);
    } else if (b < 192) {
        int idx = (b - 128) * 256 + t;
        int n = idx >> 7, k = idx & 127;
        Wt2p[n * 128 + k] = f2bf(Wp2[k * 128 + n]);
    } else {
        int idx = (b - 192) * 256 + t;
        int n = idx >> 7, k = idx & 127;
        Wt2v[n * 128 + k] = f2bf(Wv2[k * 128 + n]);
    }
}

// ---------------- layer-1 MFMA GEMM: C[N,256] = bf16(x[N,128]) @ [Wp1|Wv1] -----------
// 4 waves/block, wave = 16-row strip; A streamed from global fp32, cvt_pk -> bf16.
// W (transposed, bf16) staged in 64KB LDS with XOR swizzle.
__global__ __launch_bounds__(256) void k_gemm1(const float* __restrict__ X,
                                               const ushort_t* __restrict__ Wt1,
                                               ushort_t* __restrict__ C, int nrows) {
    __shared__ ushort_t Wl[256 * 128];
    int t = threadIdx.x;
    const ushortx8* Wg = (const ushortx8*)Wt1;
#pragma unroll
    for (int i = 0; i < 16; ++i) {
        int c = i * 256 + t;
        int row = c >> 4, slot = c & 15;
        int db = row * 256 + ((slot * 16) ^ ((row & 7) << 4));
        *(ushortx8*)((char*)Wl + db) = Wg[c];
    }
    __syncthreads();

    int w = t >> 6, l = t & 63, m = l & 15, g = l >> 4;
    int r0 = blockIdx.x * 64 + w * 16;
    if (r0 >= nrows) return;   // 50000 = 781*64 + 16 -> whole-strip OOB only

    const float* Arow = X + (size_t)(r0 + m) * 128;
    bf16x8 af[4];
#pragma unroll
    for (int kk = 0; kk < 4; ++kk) {
        float4 lo = *(const float4*)(Arow + kk * 32 + g * 8);
        float4 hi = *(const float4*)(Arow + kk * 32 + g * 8 + 4);
        union { unsigned u[4]; bf16x8 v; } cv;
        cv.u[0] = cvtpk(lo.x, lo.y);
        cv.u[1] = cvtpk(lo.z, lo.w);
        cv.u[2] = cvtpk(hi.x, hi.y);
        cv.u[3] = cvtpk(hi.z, hi.w);
        af[kk] = cv.v;
    }

    f32x4 acc[16];
#pragma unroll
    for (int nt = 0; nt < 16; ++nt) acc[nt] = (f32x4){0.f, 0.f, 0.f, 0.f};
    int sw = (m & 7) << 4;
#pragma unroll
    for (int nt = 0; nt < 16; ++nt) {
        const char* Wb = (const char*)Wl + (nt * 16 + m) * 256;
#pragma unroll
        for (int kk = 0; kk < 4; ++kk) {
            bf16x8 wf = *(const bf16x8*)(Wb + ((kk * 64 + g * 16) ^ sw));
            acc[nt] = __builtin_amdgcn_mfma_f32_16x16x32_bf16(wf, af[kk], acc[nt], 0, 0, 0);
        }
    }
#pragma unroll
    for (int nt = 0; nt < 16; ++nt) {
        ushortx4 o = {f2bf(acc[nt][0]), f2bf(acc[nt][1]), f2bf(acc[nt][2]), f2bf(acc[nt][3])};
        *(ushortx4*)(C + (size_t)(r0 + m) * 256 + nt * 16 + g * 4) = o;
    }
}

// ---------------- layer-2 dual MFMA GEMM (block-diagonal 256 -> 256) ----------------
__global__ __launch_bounds__(256) void k_gemm2(const ushort_t* __restrict__ A,
                                               const ushort_t* __restrict__ Wp,
                                               const ushort_t* __restrict__ Wv,
                                               ushort_t* __restrict__ C, int nrows) {
    __shared__ ushort_t Wl[2 * 128 * 128];
    int t = threadIdx.x;
    const ushortx8* Wgp = (const ushortx8*)Wp;
    const ushortx8* Wgv = (const ushortx8*)Wv;
#pragma unroll
    for (int i = 0; i < 8; ++i) {
        int c = i * 256 + t;
        int row = c >> 4, slot = c & 15;
        int db = row * 256 + ((slot * 16) ^ ((row & 7) << 4));
        *(ushortx8*)((char*)Wl + db) = Wgp[c];
        *(ushortx8*)((char*)Wl + 32768 + db) = Wgv[c];
    }
    __syncthreads();

    int w = t >> 6, l = t & 63, m = l & 15, g = l >> 4;
    int r0 = blockIdx.x * 64 + w * 16;
    if (r0 >= nrows) return;

    const ushort_t* Arow = A + (size_t)(r0 + m) * 256;
    bf16x8 alo[4], ahi[4];
#pragma unroll
    for (int kk = 0; kk < 4; ++kk) {
        alo[kk] = *(const bf16x8*)(Arow + kk * 32 + g * 8);
        ahi[kk] = *(const bf16x8*)(Arow + 128 + kk * 32 + g * 8);
    }

    f32x4 accp[8], accv[8];
#pragma unroll
    for (int nt = 0; nt < 8; ++nt) {
        accp[nt] = (f32x4){0.f, 0.f, 0.f, 0.f};
        accv[nt] = (f32x4){0.f, 0.f, 0.f, 0.f};
    }
    int sw = (m & 7) << 4;
#pragma unroll
    for (int nt = 0; nt < 8; ++nt) {
        const char* Wbp = (const char*)Wl + (nt * 16 + m) * 256;
        const char* Wbv = Wbp + 32768;
#pragma unroll
        for (int kk = 0; kk < 4; ++kk) {
            int off = (kk * 64 + g * 16) ^ sw;
            bf16x8 wfp = *(const bf16x8*)(Wbp + off);
            accp[nt] = __builtin_amdgcn_mfma_f32_16x16x32_bf16(wfp, alo[kk], accp[nt], 0, 0, 0);
            bf16x8 wfv = *(const bf16x8*)(Wbv + off);
            accv[nt] = __builtin_amdgcn_mfma_f32_16x16x32_bf16(wfv, ahi[kk], accv[nt], 0, 0, 0);
        }
    }
#pragma unroll
    for (int nt = 0; nt < 8; ++nt) {
        ushortx4 op = {f2bf(accp[nt][0]), f2bf(accp[nt][1]), f2bf(accp[nt][2]), f2bf(accp[nt][3])};
        ushortx4 ov = {f2bf(accv[nt][0]), f2bf(accv[nt][1]), f2bf(accv[nt][2]), f2bf(accv[nt][3])};
        *(ushortx4*)(C + (size_t)(r0 + m) * 256 + nt * 16 + g * 4) = op;
        *(ushortx4*)(C + (size_t)(r0 + m) * 256 + 128 + nt * 16 + g * 4) = ov;
    }
}

// ---------------- fused aggregation, 256 features, bf16 in/out ----------------
__global__ __launch_bounds__(256) void k_agg256(const ushort_t* __restrict__ H,
                                                ushort_t* __restrict__ OUT,
                                                const float* __restrict__ b_lo,
                                                const float* __restrict__ b_hi,
                                                const float* __restrict__ dinv,
                                                const int* __restrict__ rowptr,
                                                const int* __restrict__ cnt,
                                                const int2* __restrict__ edges) {
    int wv = threadIdx.x >> 6;
    int l = threadIdx.x & 63;
    int i = blockIdx.x * 4 + wv;
    if (i >= NN) return;
    int h = l >> 5, q = l & 31;
    const ushortx8* H8 = (const ushortx8*)H;

    float a0[8] = {}, a1[8] = {};
    float di = dinv[i];
    if (h == 0) {
        float ws = di * di;
        ushortx8 hv = H8[(size_t)i * 32 + q];
#pragma unroll
        for (int k = 0; k < 8; ++k) a0[k] = ws * bf2f(hv[k]);
    }
    int st = rowptr[i];
    int n = cnt[i];
    int j = h;
    for (; j + 6 < n; j += 8) {
        int2 e0 = edges[st + j], e1 = edges[st + j + 2];
        int2 e2 = edges[st + j + 4], e3 = edges[st + j + 6];
        float w0 = __int_as_float(e0.y), w1 = __int_as_float(e1.y);
        float w2 = __int_as_float(e2.y), w3 = __int_as_float(e3.y);
        ushortx8 h0 = H8[(size_t)e0.x * 32 + q];
        ushortx8 h1 = H8[(size_t)e1.x * 32 + q];
        ushortx8 h2 = H8[(size_t)e2.x * 32 + q];
        ushortx8 h3 = H8[(size_t)e3.x * 32 + q];
#pragma unroll
        for (int k = 0; k < 8; ++k) a0[k] += w0 * bf2f(h0[k]);
#pragma unroll
        for (int k = 0; k < 8; ++k) a1[k] += w1 * bf2f(h1[k]);
#pragma unroll
        for (int k = 0; k < 8; ++k) a0[k] += w2 * bf2f(h2[k]);
#pragma unroll
        for (int k = 0; k < 8; ++k) a1[k] += w3 * bf2f(h3[k]);
    }
    for (; j < n; j += 2) {
        int2 e0 = edges[st + j];
        float w0 = __int_as_float(e0.y);
        ushortx8 h0 = H8[(size_t)e0.x * 32 + q];
#pragma unroll
        for (int k = 0; k < 8; ++k) a0[k] += w0 * bf2f(h0[k]);
    }
#pragma unroll
    for (int k = 0; k < 8; ++k) a0[k] += a1[k];
#pragma unroll
    for (int k = 0; k < 8; ++k) a0[k] += __shfl_xor(a0[k], 32, 64);

    if (h == 0) {
        const float* bb = (q < 16) ? (b_lo + q * 8) : (b_hi + (q - 16) * 8);
        float4 b0 = *(const float4*)bb;
        float4 b1 = *(const float4*)(bb + 4);
        float r[8];
        r[0] = fmaxf(a0[0] + b0.x, 0.f); r[1] = fmaxf(a0[1] + b0.y, 0.f);
        r[2] = fmaxf(a0[2] + b0.z, 0.f); r[3] = fmaxf(a0[3] + b0.w, 0.f);
        r[4] = fmaxf(a0[4] + b1.x, 0.f); r[5] = fmaxf(a0[5] + b1.y, 0.f);
        r[6] = fmaxf(a0[6] + b1.z, 0.f); r[7] = fmaxf(a0[7] + b1.w, 0.f);
        ushortx8 o = {f2bf(r[0]), f2bf(r[1]), f2bf(r[2]), f2bf(r[3]),
                      f2bf(r[4]), f2bf(r[5]), f2bf(r[6]), f2bf(r[7])};
        ((ushortx8*)OUT)[(size_t)i * 32 + q] = o;
    }
}

// ---------------- small GEMM (bf16 in): fs[:,0:8]=f2[:,0:128]@Wp3 ; fs[:,8]=f2[:,128:256]@Wv3
__global__ __launch_bounds__(256) void k_small(const ushort_t* __restrict__ F2,
                                               const float* __restrict__ Wp3,
                                               const float* __restrict__ Wv3,
                                               float* __restrict__ FS) {
    __shared__ float Wp[8 * 128];
    __shared__ float Wv[128];
    int t = threadIdx.x;
    for (int j = t; j < 1024; j += 256) {
        int k = j >> 3, c = j & 7;
        Wp[c * 128 + k] = Wp3[j];
    }
    if (t < 128) Wv[t] = Wv3[t];
    __syncthreads();
    int row = blockIdx.x * 256 + t;
    if (row >= NN) return;
    const ushortx8* F8 = (const ushortx8*)F2;
    size_t base = (size_t)row * 32;
    float acc[9] = {};
#pragma unroll 2
    for (int kc = 0; kc < 16; ++kc) {
        ushortx8 p = F8[base + kc];
        ushortx8 v = F8[base + 16 + kc];
#pragma unroll
        for (int jj = 0; jj < 8; ++jj) {
            float pv = bf2f(p[jj]);
            int k = kc * 8 + jj;
#pragma unroll
            for (int c = 0; c < 8; ++c) acc[c] += pv * Wp[c * 128 + k];
            acc[8] += bf2f(v[jj]) * Wv[k];
        }
    }
    float4* FSo = (float4*)(FS + (size_t)row * 12);
    float4 o0 = {acc[0], acc[1], acc[2], acc[3]};
    float4 o1 = {acc[4], acc[5], acc[6], acc[7]};
    float4 o2 = {acc[8], 0.f, 0.f, 0.f};
    FSo[0] = o0; FSo[1] = o1; FSo[2] = o2;
}

// ---------------- final fused aggregation (8 logits + 1 value) ----------------
__global__ void k_agg9(const float* __restrict__ FS, float* __restrict__ out_logits,
                       float* __restrict__ out_v, const float* __restrict__ bp3,
                       const float* __restrict__ bv3, const float* __restrict__ dinv,
                       const int* __restrict__ rowptr, const int* __restrict__ cnt,
                       const int2* __restrict__ edges) {
    int i = blockIdx.x * 256 + threadIdx.x;
    if (i >= NN) return;
    float di = dinv[i];
    float w0 = di * di;
    const float4* F = (const float4*)FS;
    size_t b0 = (size_t)i * 3;
    float4 x0 = F[b0], x1 = F[b0 + 1], x2 = F[b0 + 2];
    float a[9];
    a[0] = w0 * x0.x; a[1] = w0 * x0.y; a[2] = w0 * x0.z; a[3] = w0 * x0.w;
    a[4] = w0 * x1.x; a[5] = w0 * x1.y; a[6] = w0 * x1.z; a[7] = w0 * x1.w;
    a[8] = w0 * x2.x;
    int st = rowptr[i];
    int n = cnt[i];
    for (int j = 0; j < n; ++j) {
        int2 e = edges[st + j];
        float w = __int_as_float(e.y);
        size_t sb = (size_t)e.x * 3;
        float4 y0 = F[sb], y1 = F[sb + 1], y2 = F[sb + 2];
        a[0] += w * y0.x; a[1] += w * y0.y; a[2] += w * y0.z; a[3] += w * y0.w;
        a[4] += w * y1.x; a[5] += w * y1.y; a[6] += w * y1.z; a[7] += w * y1.w;
        a[8] += w * y2.x;
    }
    float4 bpa = *(const float4*)bp3;
    float4 bpb = *(const float4*)(bp3 + 4);
    float4 o0 = {a[0] + bpa.x, a[1] + bpa.y, a[2] + bpa.z, a[3] + bpa.w};
    float4 o1 = {a[4] + bpb.x, a[5] + bpb.y, a[6] + bpb.z, a[7] + bpb.w};
    ((float4*)out_logits)[(size_t)i * 2] = o0;
    ((float4*)out_logits)[(size_t)i * 2 + 1] = o1;
    out_v[i] = a[8] + bv3[0];
}

// ---------------- launcher ----------------
extern "C" void kernel_launch(void* const* d_in, const int* in_sizes, int n_in,
                              void* d_out, int out_size, void* d_ws, size_t ws_size,
                              hipStream_t stream) {
    const float* x   = (const float*)d_in[0];
    const int*   ei  = (const int*)d_in[1];
    const float* Wp1 = (const float*)d_in[2],  *bp1 = (const float*)d_in[3];
    const float* Wp2 = (const float*)d_in[4],  *bp2 = (const float*)d_in[5];
    const float* Wp3 = (const float*)d_in[6],  *bp3 = (const float*)d_in[7];
    const float* Wv1 = (const float*)d_in[8],  *bv1 = (const float*)d_in[9];
    const float* Wv2 = (const float*)d_in[10], *bv2 = (const float*)d_in[11];
    const float* Wv3 = (const float*)d_in[12], *bv3 = (const float*)d_in[13];
    float* out_logits = (float*)d_out;
    float* out_v = (float*)d_out + (size_t)NN * 8;

    char* w = (char*)d_ws;
    auto alloc = [&](size_t bytes) {
        char* p = w;
        w += (bytes + 255) & ~(size_t)255;
        return p;
    };
    int*      cntfill = (int*)alloc((size_t)2 * NN * 4);   // cnt | fill, zeroed together
    int*      cnt    = cntfill;
    int*      fill   = cntfill + NN;
    int*      rowptr = (int*)alloc(NN * 4);
    int*      bsum   = (int*)alloc(256 * 4);
    int*      boff   = (int*)alloc(256 * 4);
    float*    dinv   = (float*)alloc(NN * 4);
    int2*     edges  = (int2*)alloc((size_t)NE * 8);
    ushort_t* Wt1    = (ushort_t*)alloc(256 * 128 * 2);
    ushort_t* Wt2p   = (ushort_t*)alloc(128 * 128 * 2);
    ushort_t* Wt2v   = (ushort_t*)alloc(128 * 128 * 2);
    ushort_t* Hb     = (ushort_t*)alloc((size_t)NN * 256 * 2);
    ushort_t* f1b    = (ushort_t*)alloc((size_t)NN * 256 * 2);
    ushort_t* f2b    = (ushort_t*)alloc((size_t)NN * 256 * 2);
    float*    fs     = (float*)alloc((size_t)NN * 12 * 4);

    const int NB = (NN + 255) / 256;   // 196
    const int EB = (NE + 255) / 256;
    const int GB = (NN + 63) / 64;     // 782
    const int AB = NN / 4;             // 12500

    hipMemsetAsync(cntfill, 0, (size_t)2 * NN * 4, stream);
    k_count<<<EB, 256, 0, stream>>>(ei, cnt);
    k_scan1<<<NB, 256, 0, stream>>>(cnt, rowptr, bsum, dinv);
    k_scan2<<<1, 256, 0, stream>>>(bsum, boff, NB);
    k_scan3<<<NB, 256, 0, stream>>>(rowptr, boff);
    k_fill<<<EB, 256, 0, stream>>>(ei, rowptr, fill, dinv, edges);

    k_prep_w<<<256, 256, 0, stream>>>(Wp1, Wv1, Wp2, Wv2, Wt1, Wt2p, Wt2v);

    // layer 1 (policy | value fused into 256 cols)
    k_gemm1<<<GB, 256, 0, stream>>>(x, Wt1, Hb, NN);
    k_agg256<<<AB, 256, 0, stream>>>(Hb, f1b, bp1, bv1, dinv, rowptr, cnt, edges);
    // layer 2 (block-diagonal, fused)
    k_gemm2<<<GB, 256, 0, stream>>>(f1b, Wt2p, Wt2v, Hb, NN);
    k_agg256<<<AB, 256, 0, stream>>>(Hb, f2b, bp2, bv2, dinv, rowptr, cnt, edges);
    // layer 3 (fp32 accumulate from bf16 input)
    k_small<<<NB, 256, 0, stream>>>(f2b, Wp3, Wv3, fs);
    k_agg9<<<NB, 256, 0, stream>>>(fs, out_logits, out_v, bp3, bv3, dinv, rowptr, cnt, edges);
}